// Round 1
// baseline (182.263 us; speedup 1.0000x reference)
//
#include <hip/hip_runtime.h>

#define B_TOTAL 131072
#define DIM 256
#define NCAT 10

// ws layout in floats
#define WS_SUMS    0        // [10][256]
#define WS_COUNTS  2560     // [16] (10 used)
#define WS_PUSED   2592     // [10][256]
#define WS_PARTIAL 5152     // [K3_BLOCKS]

#define K1_BLOCKS 768
#define K3_BLOCKS 2048

__device__ __forceinline__ float waveRedSum(float v) {
#pragma unroll
  for (int m = 1; m < 64; m <<= 1) v += __shfl_xor(v, m, 64);
  return v;
}

// ---------------- K1: row-normalize + segment sum/count ----------------
__global__ __launch_bounds__(256) void k1_segsum(
    const float* __restrict__ feats, const int* __restrict__ cats,
    float* __restrict__ ws) {
  __shared__ float acc[4][NCAT * DIM];   // 40 KB, per-wave private
  __shared__ float accCnt[4][16];

  const int tid = threadIdx.x;
  const int w = tid >> 6;
  const int lane = tid & 63;

  for (int i = tid; i < 4 * NCAT * DIM; i += 256) (&acc[0][0])[i] = 0.0f;
  if (tid < 64) (&accCnt[0][0])[tid] = 0.0f;
  __syncthreads();

  const int waveId = blockIdx.x * 4 + w;
  const int stride = gridDim.x * 4;

  int row = waveId;
  float4 cur = make_float4(0.f, 0.f, 0.f, 0.f);
  if (row < B_TOTAL)
    cur = *(const float4*)(feats + (size_t)row * DIM + lane * 4);

  while (row < B_TOTAL) {
    const int nrow = row + stride;
    float4 nxt = make_float4(0.f, 0.f, 0.f, 0.f);
    if (nrow < B_TOTAL)
      nxt = *(const float4*)(feats + (size_t)nrow * DIM + lane * 4);

    const int cat = cats[row];
    float ss = cur.x * cur.x + cur.y * cur.y + cur.z * cur.z + cur.w * cur.w;
    ss = waveRedSum(ss);
    const float inv = 1.0f / fmaxf(sqrtf(ss), 1e-12f);

    float4* dst = (float4*)&acc[w][cat * DIM + lane * 4];
    float4 t = *dst;
    t.x += cur.x * inv; t.y += cur.y * inv;
    t.z += cur.z * inv; t.w += cur.w * inv;
    *dst = t;
    if (lane == 0) accCnt[w][cat] += 1.0f;

    row = nrow;
    cur = nxt;
  }
  __syncthreads();

  float* sums = ws + WS_SUMS;
  float* counts = ws + WS_COUNTS;
  for (int i = tid; i < NCAT * DIM; i += 256) {
    const float t = acc[0][i] + acc[1][i] + acc[2][i] + acc[3][i];
    atomicAdd(&sums[i], t);
  }
  if (tid < NCAT) {
    const float t = accCnt[0][tid] + accCnt[1][tid] + accCnt[2][tid] + accCnt[3][tid];
    atomicAdd(&counts[tid], t);
  }
}

// ---------------- K2: prototype EMA update -> p_used ----------------
__global__ __launch_bounds__(640) void k2_proto(
    const float* __restrict__ protos, float* __restrict__ ws) {
  const int tid = threadIdx.x;          // 640 = 10 waves, one per category
  const int c = tid >> 6;
  const int lane = tid & 63;
  if (c >= NCAT) return;

  const float* sums = ws + WS_SUMS;
  const float* counts = ws + WS_COUNTS;
  float* pused = ws + WS_PUSED;

  const float cnt = counts[c];
  const float cmax = fmaxf(cnt, 1.0f);

  const float4 s = *(const float4*)(sums + c * DIM + lane * 4);
  const float4 p = *(const float4*)(protos + c * DIM + lane * 4);

  float4 v;
  v.x = 0.9f * p.x + 0.1f * (s.x / cmax);
  v.y = 0.9f * p.y + 0.1f * (s.y / cmax);
  v.z = 0.9f * p.z + 0.1f * (s.z / cmax);
  v.w = 0.9f * p.w + 0.1f * (s.w / cmax);

  float ss = v.x * v.x + v.y * v.y + v.z * v.z + v.w * v.w;
  ss = waveRedSum(ss);
  const float n = fmaxf(sqrtf(ss), 1e-12f);

  float4 upd;
  if (cnt > 0.0f) {
    upd.x = v.x / n; upd.y = v.y / n; upd.z = v.z / n; upd.w = v.w / n;
  } else {
    upd = p;
  }
  // torch-style: prototypes + (updated - prototypes)
  float4 pu;
  pu.x = p.x + (upd.x - p.x);
  pu.y = p.y + (upd.y - p.y);
  pu.z = p.z + (upd.z - p.z);
  pu.w = p.w + (upd.w - p.w);
  *(float4*)(pused + c * DIM + lane * 4) = pu;
}

// ---------------- K3: sim + logsoftmax loss + aligned output ----------------
__global__ __launch_bounds__(256) void k3_main(
    const float* __restrict__ feats, const int* __restrict__ cats,
    const float* __restrict__ ws_ro, float* __restrict__ out,
    float* __restrict__ partials) {
  // transposed prototypes: pT[(c*64+lane)*4 + k] = p_used[c][lane + 64k]
  __shared__ float pT[NCAT * 64 * 4];   // 10 KB
  __shared__ float wloss[4];

  const int tid = threadIdx.x;
  const int w = tid >> 6;
  const int lane = tid & 63;
  const float* pused = ws_ro + WS_PUSED;

  for (int i = tid; i < NCAT * 64; i += 256) {
    const int c = i >> 6;
    const int l = i & 63;
    float4 t;
    t.x = pused[c * DIM + l];
    t.y = pused[c * DIM + l + 64];
    t.z = pused[c * DIM + l + 128];
    t.w = pused[c * DIM + l + 192];
    *(float4*)&pT[i * 4] = t;
  }
  __syncthreads();

  constexpr float INV_T = 1.0f / 0.07f;
  float lossAcc = 0.0f;

  const int waveId = blockIdx.x * 4 + w;
  const int stride = gridDim.x * 4;

  int row = waveId;
  float n0 = 0.f, n1 = 0.f, n2 = 0.f, n3 = 0.f;
  if (row < B_TOTAL) {
    const float* b = feats + (size_t)row * DIM;
    n0 = b[lane]; n1 = b[lane + 64]; n2 = b[lane + 128]; n3 = b[lane + 192];
  }

  while (row < B_TOTAL) {
    float f0 = n0, f1 = n1, f2 = n2, f3 = n3;
    const int cat = cats[row];
    const int nrow = row + stride;
    if (nrow < B_TOTAL) {
      const float* b = feats + (size_t)nrow * DIM;
      n0 = b[lane]; n1 = b[lane + 64]; n2 = b[lane + 128]; n3 = b[lane + 192];
    }

    // normalize f
    float ss = f0 * f0 + f1 * f1 + f2 * f2 + f3 * f3;
    ss = waveRedSum(ss);
    const float inv = 1.0f / fmaxf(sqrtf(ss), 1e-12f);
    f0 *= inv; f1 *= inv; f2 *= inv; f3 *= inv;

    // 10 dot products
    float sim[NCAT];
#pragma unroll
    for (int c = 0; c < NCAT; c++) {
      const float4 p = *(const float4*)&pT[(c * 64 + lane) * 4];
      sim[c] = f0 * p.x + f1 * p.y + f2 * p.z + f3 * p.w;
    }
#pragma unroll
    for (int c = 0; c < NCAT; c++) {
      float v = sim[c];
#pragma unroll
      for (int m = 1; m < 64; m <<= 1) v += __shfl_xor(v, m, 64);
      sim[c] = v * INV_T;
    }

    // log-softmax over 10 (all lanes redundantly; values are uniform)
    float mx = sim[0];
#pragma unroll
    for (int c = 1; c < NCAT; c++) mx = fmaxf(mx, sim[c]);
    float se = 0.0f;
    float st = 0.0f;   // sim[cat] via unrolled select (no runtime reg indexing)
#pragma unroll
    for (int c = 0; c < NCAT; c++) {
      se += expf(sim[c] - mx);
      st = (c == cat) ? sim[c] : st;
    }
    const float lse = mx + logf(se);
    lossAcc += (lse - st);

    // aligned = l2norm(0.7 f + 0.3 p_used[cat])
    const float4 pc = *(const float4*)&pT[(cat * 64 + lane) * 4];
    float a0 = 0.7f * f0 + 0.3f * pc.x;
    float a1 = 0.7f * f1 + 0.3f * pc.y;
    float a2 = 0.7f * f2 + 0.3f * pc.z;
    float a3 = 0.7f * f3 + 0.3f * pc.w;
    float s2 = a0 * a0 + a1 * a1 + a2 * a2 + a3 * a3;
    s2 = waveRedSum(s2);
    const float inv2 = 1.0f / fmaxf(sqrtf(s2), 1e-12f);

    float* ob = out + 1 + (size_t)row * DIM;
    ob[lane]       = a0 * inv2;
    ob[lane + 64]  = a1 * inv2;
    ob[lane + 128] = a2 * inv2;
    ob[lane + 192] = a3 * inv2;

    row = nrow;
  }

  // deterministic per-block loss partial (all lanes hold same lossAcc)
  if (lane == 0) wloss[w] = lossAcc;
  __syncthreads();
  if (tid == 0)
    partials[blockIdx.x] = wloss[0] + wloss[1] + wloss[2] + wloss[3];
}

// ---------------- K4: final loss reduction ----------------
__global__ __launch_bounds__(256) void k4_loss(
    const float* __restrict__ partials, float* __restrict__ out) {
  __shared__ float red[4];
  const int tid = threadIdx.x;
  const int w = tid >> 6;
  const int lane = tid & 63;
  float s = 0.0f;
  for (int i = tid; i < K3_BLOCKS; i += 256) s += partials[i];
  s = waveRedSum(s);
  if (lane == 0) red[w] = s;
  __syncthreads();
  if (tid == 0)
    out[0] = (red[0] + red[1] + red[2] + red[3]) * (1.0f / (float)B_TOTAL);
}

extern "C" void kernel_launch(void* const* d_in, const int* in_sizes, int n_in,
                              void* d_out, int out_size, void* d_ws, size_t ws_size,
                              hipStream_t stream) {
  const float* feats = (const float*)d_in[0];
  const int* cats = (const int*)d_in[1];
  const float* protos = (const float*)d_in[2];
  float* out = (float*)d_out;
  float* ws = (float*)d_ws;

  // zero segment-sum + count accumulators
  hipMemsetAsync(ws, 0, (WS_COUNTS + 16) * sizeof(float), stream);

  k1_segsum<<<K1_BLOCKS, 256, 0, stream>>>(feats, cats, ws);
  k2_proto<<<1, 640, 0, stream>>>(protos, ws);
  k3_main<<<K3_BLOCKS, 256, 0, stream>>>(feats, cats, ws, out, ws + WS_PARTIAL);
  k4_loss<<<1, 256, 0, stream>>>(ws + WS_PARTIAL, out);
}

// Round 2
// 130.281 us; speedup vs baseline: 1.3990x; 1.3990x over previous
//
#include <hip/hip_runtime.h>

#define B_TOTAL 131072
#define DIM 256
#define NCAT 10

// ws layout in floats
#define WS_SUMS    0        // [10][256]
#define WS_COUNTS  2560     // [16] (10 used)
#define WS_PUSED   2592     // [10][256]
#define WS_PARTIAL 5152     // [K3_BLOCKS]

#define K1_BLOCKS 768
#define K3_BLOCKS 2048

typedef __attribute__((ext_vector_type(8))) short bf16x8;
typedef __attribute__((ext_vector_type(4))) float f32x4;

union Frag { bf16x8 v; unsigned u[4]; };

__device__ __forceinline__ float waveRedSum(float v) {
#pragma unroll
  for (int m = 1; m < 64; m <<= 1) v += __shfl_xor(v, m, 64);
  return v;
}

// pack two fp32 -> packed bf16 pair (RNE, finite inputs)
__device__ __forceinline__ unsigned pk2(float a, float b) {
  unsigned ua = __float_as_uint(a), ub = __float_as_uint(b);
  ua = (ua + 0x7fffu + ((ua >> 16) & 1u)) >> 16;
  ub = (ub + 0x7fffu + ((ub >> 16) & 1u)) >> 16;
  return ua | (ub << 16);
}

// ---------------- K1: row-normalize + segment sum/count ----------------
__global__ __launch_bounds__(256) void k1_segsum(
    const float* __restrict__ feats, const int* __restrict__ cats,
    float* __restrict__ ws) {
  __shared__ float acc[4][NCAT * DIM];   // 40 KB, per-wave private
  __shared__ float accCnt[4][16];

  const int tid = threadIdx.x;
  const int w = tid >> 6;
  const int lane = tid & 63;

  for (int i = tid; i < 4 * NCAT * DIM; i += 256) (&acc[0][0])[i] = 0.0f;
  if (tid < 64) (&accCnt[0][0])[tid] = 0.0f;
  __syncthreads();

  const int waveId = blockIdx.x * 4 + w;
  const int stride = gridDim.x * 4;

  int row = waveId;
  float4 cur = make_float4(0.f, 0.f, 0.f, 0.f);
  if (row < B_TOTAL)
    cur = *(const float4*)(feats + (size_t)row * DIM + lane * 4);

  while (row < B_TOTAL) {
    const int nrow = row + stride;
    float4 nxt = make_float4(0.f, 0.f, 0.f, 0.f);
    if (nrow < B_TOTAL)
      nxt = *(const float4*)(feats + (size_t)nrow * DIM + lane * 4);

    const int cat = cats[row];
    float ss = cur.x * cur.x + cur.y * cur.y + cur.z * cur.z + cur.w * cur.w;
    ss = waveRedSum(ss);
    const float inv = __builtin_amdgcn_rsqf(fmaxf(ss, 1e-24f));

    float4* dst = (float4*)&acc[w][cat * DIM + lane * 4];
    float4 t = *dst;
    t.x += cur.x * inv; t.y += cur.y * inv;
    t.z += cur.z * inv; t.w += cur.w * inv;
    *dst = t;
    if (lane == 0) accCnt[w][cat] += 1.0f;

    row = nrow;
    cur = nxt;
  }
  __syncthreads();

  float* sums = ws + WS_SUMS;
  float* counts = ws + WS_COUNTS;
  for (int i = tid; i < NCAT * DIM; i += 256) {
    const float t = acc[0][i] + acc[1][i] + acc[2][i] + acc[3][i];
    atomicAdd(&sums[i], t);
  }
  if (tid < NCAT) {
    const float t = accCnt[0][tid] + accCnt[1][tid] + accCnt[2][tid] + accCnt[3][tid];
    atomicAdd(&counts[tid], t);
  }
}

// ---------------- K2: prototype EMA update -> p_used ----------------
__global__ __launch_bounds__(640) void k2_proto(
    const float* __restrict__ protos, float* __restrict__ ws) {
  const int tid = threadIdx.x;          // 640 = 10 waves, one per category
  const int c = tid >> 6;
  const int lane = tid & 63;
  if (c >= NCAT) return;

  const float* sums = ws + WS_SUMS;
  const float* counts = ws + WS_COUNTS;
  float* pused = ws + WS_PUSED;

  const float cnt = counts[c];
  const float cmax = fmaxf(cnt, 1.0f);

  const float4 s = *(const float4*)(sums + c * DIM + lane * 4);
  const float4 p = *(const float4*)(protos + c * DIM + lane * 4);

  float4 v;
  v.x = 0.9f * p.x + 0.1f * (s.x / cmax);
  v.y = 0.9f * p.y + 0.1f * (s.y / cmax);
  v.z = 0.9f * p.z + 0.1f * (s.z / cmax);
  v.w = 0.9f * p.w + 0.1f * (s.w / cmax);

  float ss = v.x * v.x + v.y * v.y + v.z * v.z + v.w * v.w;
  ss = waveRedSum(ss);
  const float n = fmaxf(sqrtf(ss), 1e-12f);

  float4 upd;
  if (cnt > 0.0f) {
    upd.x = v.x / n; upd.y = v.y / n; upd.z = v.z / n; upd.w = v.w / n;
  } else {
    upd = p;
  }
  // torch-style: prototypes + (updated - prototypes)
  float4 pu;
  pu.x = p.x + (upd.x - p.x);
  pu.y = p.y + (upd.y - p.y);
  pu.z = p.z + (upd.z - p.z);
  pu.w = p.w + (upd.w - p.w);
  *(float4*)(pused + c * DIM + lane * 4) = pu;
}

// ---------------- K3: MFMA sims + logsoftmax loss + aligned output ----------------
// One wave handles a 16-row tile. A-frag: lane l -> row (l&15), k=(l>>4)*8+j+32s.
// B-frag: lane l -> cat (l&15) (zero-pad cats 10..15), same k mapping.
// D: col(cat)=lane&15, row=(lane>>4)*4+reg.
__global__ __launch_bounds__(256) void k3_main(
    const float* __restrict__ feats, const int* __restrict__ cats,
    const float* __restrict__ ws_ro, float* __restrict__ out,
    float* __restrict__ partials) {
  __shared__ float p_lds[NCAT * 260];    // fp32 prototypes, stride 260 (bank spread)
  __shared__ float wloss[4];

  const int tid = threadIdx.x;
  const int w = tid >> 6;
  const int l = tid & 63;
  const int q = l >> 4;        // k-group
  const int mr = l & 15;       // this lane's A-row / B-cat index
  const float* pused = ws_ro + WS_PUSED;

  for (int i = tid; i < NCAT * 260; i += 256) {
    const int c = i / 260, k = i - c * 260;
    p_lds[i] = (k < 256) ? pused[c * 256 + k] : 0.0f;
  }
  __syncthreads();

  // B fragments (prototypes as bf16), loaded once per wave
  Frag bfr[8];
  {
    const float* prow = pused + mr * 256;
#pragma unroll
    for (int s = 0; s < 8; s++) {
      float4 b0 = make_float4(0.f, 0.f, 0.f, 0.f), b1 = b0;
      const int kb = q * 8 + 32 * s;
      if (mr < NCAT) {
        b0 = *(const float4*)(prow + kb);
        b1 = *(const float4*)(prow + kb + 4);
      }
      bfr[s].u[0] = pk2(b0.x, b0.y); bfr[s].u[1] = pk2(b0.z, b0.w);
      bfr[s].u[2] = pk2(b1.x, b1.y); bfr[s].u[3] = pk2(b1.z, b1.w);
    }
  }

  constexpr float KZ = (1.0f / 0.07f) * 1.44269504088896f; // 1/T * log2(e)
  constexpr float LN2 = 0.69314718056f;
  float lossAcc = 0.0f;

  const int waveG = blockIdx.x * 4 + w;
  const int nwaves = gridDim.x * 4;

  for (int t = waveG; t < B_TOTAL / 16; t += nwaves) {
    const int r0 = t * 16;

    // ---- load F tile (raw fp32), sumsq, convert to bf16 A-frags ----
    const float* frow = feats + (size_t)(r0 + mr) * DIM;
    Frag afr[8];
    float ss = 0.0f;
#pragma unroll
    for (int s = 0; s < 8; s++) {
      const int kb = q * 8 + 32 * s;
      const float4 u0 = *(const float4*)(frow + kb);
      const float4 u1 = *(const float4*)(frow + kb + 4);
      ss += u0.x * u0.x + u0.y * u0.y + u0.z * u0.z + u0.w * u0.w
          + u1.x * u1.x + u1.y * u1.y + u1.z * u1.z + u1.w * u1.w;
      afr[s].u[0] = pk2(u0.x, u0.y); afr[s].u[1] = pk2(u0.z, u0.w);
      afr[s].u[2] = pk2(u1.x, u1.y); afr[s].u[3] = pk2(u1.z, u1.w);
    }
    // full row sumsq: lanes {mr, mr+16, mr+32, mr+48} each hold a quarter
    ss += __shfl_xor(ss, 16, 64);
    ss += __shfl_xor(ss, 32, 64);
    const float inv = __builtin_amdgcn_rsqf(fmaxf(ss, 1e-24f)); // 1/||f||, row mr

    // ---- sims via MFMA ----
    f32x4 acc = {0.f, 0.f, 0.f, 0.f};
#pragma unroll
    for (int s = 0; s < 8; s++)
      acc = __builtin_amdgcn_mfma_f32_16x16x32_bf16(afr[s].v, bfr[s].v, acc, 0, 0, 0);

    // ---- per-reg softmax (row r0+4q+j, lane's category = mr) ----
    float stv[4];
#pragma unroll
    for (int j = 0; j < 4; j++) {
      const float invj = __shfl(inv, 4 * q + j, 64);
      const int catj = cats[r0 + 4 * q + j];
      const float z = acc[j] * (invj * KZ);       // log2-domain logit
      float zm = (mr < NCAT) ? z : -3.0e38f;
#pragma unroll
      for (int m = 1; m < 16; m <<= 1) zm = fmaxf(zm, __shfl_xor(zm, m, 64));
      float e = (mr < NCAT) ? __builtin_amdgcn_exp2f(z - zm) : 0.0f;
      float sv = (mr == catj) ? z : 0.0f;
#pragma unroll
      for (int m = 1; m < 16; m <<= 1) {
        e += __shfl_xor(e, m, 64);
        sv += __shfl_xor(sv, m, 64);
      }
      lossAcc += LN2 * (zm + __builtin_amdgcn_logf(e) - sv);
      stv[j] = sv;   // z-domain logit of the true class, rows 4q..4q+3
    }

    // ---- aligned output for row (r0+mr) ----
    // fetch st for row mr: it lives in lane group (mr>>2), reg (mr&3)
    const int srcg = (mr >> 2) * 16;
    const float s0 = __shfl(stv[0], srcg, 64);
    const float s1 = __shfl(stv[1], srcg, 64);
    const float s2 = __shfl(stv[2], srcg, 64);
    const float s3 = __shfl(stv[3], srcg, 64);
    const int jj = mr & 3;
    const float stm = (jj == 0) ? s0 : ((jj == 1) ? s1 : ((jj == 2) ? s2 : s3));
    const float simn = stm * (0.07f * LN2);  // back to cosine similarity
    // ||0.7 f_hat + 0.3 p||^2 = 0.49 + 0.09 + 0.42 * (f_hat . p)
    const float inv2 = __builtin_amdgcn_rsqf(fmaxf(0.58f + 0.42f * simn, 1e-24f));
    const int catm = cats[r0 + mr];
    const float* prow = p_lds + catm * 260;
    const float c0 = 0.7f * inv;
    float* orow = out + 1 + (size_t)(r0 + mr) * DIM;
#pragma unroll
    for (int s = 0; s < 8; s++) {
      const int kb = q * 8 + 32 * s;
      const float4 p0 = *(const float4*)(prow + kb);
      const float4 p1 = *(const float4*)(prow + kb + 4);
      float fv[8];
#pragma unroll
      for (int h = 0; h < 4; h++) {
        const unsigned pkv = afr[s].u[h];
        fv[2 * h]     = __uint_as_float(pkv << 16);
        fv[2 * h + 1] = __uint_as_float(pkv & 0xffff0000u);
      }
      const float pv[8] = {p0.x, p0.y, p0.z, p0.w, p1.x, p1.y, p1.z, p1.w};
#pragma unroll
      for (int h = 0; h < 8; h++)
        orow[kb + h] = (c0 * fv[h] + 0.3f * pv[h]) * inv2;
    }
  }

  // each row's loss was accumulated by all 16 lanes of its group -> /16
  const float s = waveRedSum(lossAcc);
  if (l == 0) wloss[w] = s * 0.0625f;
  __syncthreads();
  if (tid == 0)
    partials[blockIdx.x] = wloss[0] + wloss[1] + wloss[2] + wloss[3];
}

// ---------------- K4: final loss reduction ----------------
__global__ __launch_bounds__(256) void k4_loss(
    const float* __restrict__ partials, float* __restrict__ out) {
  __shared__ float red[4];
  const int tid = threadIdx.x;
  const int w = tid >> 6;
  const int lane = tid & 63;
  float s = 0.0f;
  for (int i = tid; i < K3_BLOCKS; i += 256) s += partials[i];
  s = waveRedSum(s);
  if (lane == 0) red[w] = s;
  __syncthreads();
  if (tid == 0)
    out[0] = (red[0] + red[1] + red[2] + red[3]) * (1.0f / (float)B_TOTAL);
}

extern "C" void kernel_launch(void* const* d_in, const int* in_sizes, int n_in,
                              void* d_out, int out_size, void* d_ws, size_t ws_size,
                              hipStream_t stream) {
  const float* feats = (const float*)d_in[0];
  const int* cats = (const int*)d_in[1];
  const float* protos = (const float*)d_in[2];
  float* out = (float*)d_out;
  float* ws = (float*)d_ws;

  // zero segment-sum + count accumulators
  hipMemsetAsync(ws, 0, (WS_COUNTS + 16) * sizeof(float), stream);

  k1_segsum<<<K1_BLOCKS, 256, 0, stream>>>(feats, cats, ws);
  k2_proto<<<1, 640, 0, stream>>>(protos, ws);
  k3_main<<<K3_BLOCKS, 256, 0, stream>>>(feats, cats, ws, out, ws + WS_PARTIAL);
  k4_loss<<<1, 256, 0, stream>>>(ws + WS_PARTIAL, out);
}